// Round 9
// baseline (752.787 us; speedup 1.0000x reference)
//
#include <hip/hip_runtime.h>
#include <hip/hip_bf16.h>

#define T_LEN 2048
#define HDIM  64
#define BT    4            // batches per block -> 512 blocks = 2 blocks/CU
#define XS    (T_LEN + 4)  // x row stride (floats)
#define HS    72           // h_lds row stride in bf16
#define L2E   1.4426950408889634f   // log2(e)
#define L2E2  2.8853900817779268f   // 2*log2(e)

typedef __attribute__((ext_vector_type(8))) short bf16x8;
typedef __attribute__((ext_vector_type(4))) float f32x4;

__device__ __forceinline__ float rcp_f(float x)  { return __builtin_amdgcn_rcpf(x); }
__device__ __forceinline__ float exp2_f(float x) { return __builtin_amdgcn_exp2f(x); }
__device__ __forceinline__ unsigned short f2bf(float f) {
    unsigned int u = __float_as_uint(f);
    u += 0x7fffu + ((u >> 16) & 1u);
    return (unsigned short)(u >> 16);
}

// 8-wave hidden-split, BT=4, grid 512 (2 blocks/CU -> 4 waves/SIMD).
// Wave w owns hidden units 8w..8w+7 via TWO A-tiles (A-row -> W_hh row is a
// free mapping):  tile0 rows 0-7 = i-rows of its units, rows 8-15 = f-rows;
//                 tile1 rows 0-7 = g-rows,              rows 8-15 = o-rows.
// C/D row r = hi*4 + s (s = col>>2, m89-verified) -> lane owns tile-row r:
//   r<8  (lanes 0-31,  roleLo): gets (i,g) of (unit 8w+r,   batch col&3)
//   r>=8 (lanes 32-63, roleHi): gets (f,o) of (unit 8w+r-8, batch col&3)
// Lane pair (L, L^32) = same (unit,batch). roleLo computes sigma(i)*tanh(g),
// ships it via one __shfl_xor(.,32); roleHi computes sigma(f), sigma(o),
// owns c (kept scaled: cY = 2*log2e*c) and h. Nonlin stream is branch-free:
// per-row weight prescale (-L2E for sigmoid rows, +2L2E for g rows) makes
// every nonlinearity rcp(1+exp2(y)) followed by one per-lane-const fma.
// roleLo's junk h goes to LDS dump rows 4-7 (unmasked ds_write).
__global__ __launch_bounds__(512, 4) void lstm_mfma_kernel(
    const float* __restrict__ x,      // [B, T, 1]
    const float* __restrict__ W_ih,   // [4H, 1]
    const float* __restrict__ W_hh,   // [4H, H]
    const float* __restrict__ b_ih,   // [4H]
    const float* __restrict__ b_hh,   // [4H]
    const float* __restrict__ W_lin,  // [3, H]
    const float* __restrict__ b_lin,  // [3]
    float* __restrict__ out)          // [B, 3]
{
    const int tid    = threadIdx.x;
    const int lane   = tid & 63;
    const int wv     = tid >> 6;       // wave 0..7, owns units 8wv..8wv+7
    const int col    = lane & 15;
    const int hi     = lane >> 4;
    const int bq     = col & 3;        // batch serviced
    const int s      = col >> 2;       // C/D reg select
    const int r      = hi * 4 + s;     // owned tile-row 0..15
    const int j      = r & 7;
    const int roleHi = r >> 3;         // 0: (i,g) producer; 1: (f,o)+state owner
    const int unit   = 8 * wv + j;
    const int b0     = blockIdx.x * BT;

    __shared__ float sx[BT][XS];
    __shared__ short hl[2][2 * BT][HS];   // rows 0-3 real h, rows 4-7 dump
    __shared__ float red[BT][3];

    for (int i = tid; i < 2 * 2 * BT * HS; i += 512) ((short*)hl)[i] = 0;

    // ---- stage all T for the 4 batches (coalesced float4) ----
    #pragma unroll
    for (int q = 0; q < 4; ++q) {
        const int idx = q * 512 + tid;      // float4 idx 0..2047
        const int row = idx >> 9;
        const int c4  = idx & 511;
        *(float4*)&sx[row][c4 * 4] =
            ((const float4*)(x + (size_t)(b0 + row) * T_LEN))[c4];
    }

    // ---- resident A-fragments (bf16), per-row prescaled ----
    bf16x8 wf[2][2];
    {
        const int am = col;   // A-frag row (m = lane&15)
        #pragma unroll
        for (int tile = 0; tile < 2; ++tile) {
            const int Wrow = (tile == 0)
                ? ((am < 8) ? (8 * wv + am)       : (64  + 8 * wv + am - 8))
                : ((am < 8) ? (128 + 8 * wv + am) : (192 + 8 * wv + am - 8));
            const float sc = (tile == 1 && am < 8) ? L2E2 : -L2E;
            #pragma unroll
            for (int kc = 0; kc < 2; ++kc) {
                const float* p = W_hh + Wrow * HDIM + kc * 32 + hi * 8;
                bf16x8 f;
                #pragma unroll
                for (int jj = 0; jj < 8; ++jj) f[jj] = (short)f2bf(p[jj] * sc);
                wf[tile][kc] = f;
            }
        }
    }
    // per-lane selected-row constants
    const int   R0   = (roleHi ? 64 : 0) + unit;      // i-row or f-row
    const int   R1   = (roleHi ? 192 : 128) + unit;   // g-row or o-row
    const float s1   = roleHi ? -L2E : L2E2;
    const float wih0 = W_ih[R0] * -L2E, bias0 = (b_ih[R0] + b_hh[R0]) * -L2E;
    const float wih1 = W_ih[R1] * s1,   bias1 = (b_ih[R1] + b_hh[R1]) * s1;
    const float A1c  = roleHi ? 1.0f : -2.0f;   // v1 = A1c*rcp(1+e1)+B1c
    const float B1c  = roleHi ? 0.0f : 1.0f;    //  -> sigma(o) or tanh(g)

    float cY = 0.f, hf = 0.f;                   // cY = 2*log2e * c
    const int sb0 = s & 1, sb1 = s >> 1;
    const int hi8 = hi * 8;
    const int rowW = bq + (roleHi ? 0 : 4);     // dump rows for roleLo

    const f32x4 zq = {0.f, 0.f, 0.f, 0.f};

    const short* hrd0 = &hl[0][bq][0];
    const short* hrd1 = &hl[1][bq][0];
    short* hwp1 = &hl[1][rowW][unit];
    short* hwp0 = &hl[0][rowW][unit];
    const float* xp = &sx[bq][0];

    __syncthreads();   // covers hl zero-init + sx staging

#define STEP(HRD, HWP, XV) do {                                               \
    const bf16x8 hb0 = *(const bf16x8*)((HRD) + hi8);                         \
    const bf16x8 hb1 = *(const bf16x8*)((HRD) + 32 + hi8);                    \
    f32x4 a0 = __builtin_amdgcn_mfma_f32_16x16x32_bf16(wf[0][0], hb0, zq, 0, 0, 0); \
    f32x4 a1 = __builtin_amdgcn_mfma_f32_16x16x32_bf16(wf[1][0], hb0, zq, 0, 0, 0); \
    a0 = __builtin_amdgcn_mfma_f32_16x16x32_bf16(wf[0][1], hb1, a0, 0, 0, 0); \
    a1 = __builtin_amdgcn_mfma_f32_16x16x32_bf16(wf[1][1], hb1, a1, 0, 0, 0); \
    const float sel0 = sb1 ? (sb0 ? a0[3] : a0[2]) : (sb0 ? a0[1] : a0[0]);   \
    const float sel1 = sb1 ? (sb0 ? a1[3] : a1[2]) : (sb0 ? a1[1] : a1[0]);   \
    const float y0 = sel0 + (bias0 + wih0 * (XV));                            \
    const float y1 = sel1 + (bias1 + wih1 * (XV));                            \
    const float e0 = exp2_f(y0);                                              \
    const float e1 = exp2_f(y1);                                              \
    const float v0 = rcp_f(1.0f + e0);            /* sigma(i) | sigma(f) */   \
    const float v1 = A1c * rcp_f(1.0f + e1) + B1c; /* tanh(g) | sigma(o) */   \
    const float ps = v0 * v1;                      /* lo: sigma(i)*tanh(g) */ \
    const float pr = __shfl_xor(ps, 32);                                      \
    cY = v0 * cY + pr * L2E2;                      /* hi: 2L2E*c update */    \
    const float yc = fminf(cY, 92.0f);             /* tanh sat, no inf */     \
    const float e2 = exp2_f(yc);                                              \
    const float th = 1.0f - 2.0f * rcp_f(1.0f + e2);                          \
    hf = v1 * th;                                  /* hi: sigma(o)*tanh(c) */ \
    unsigned int rr;                                                          \
    asm("v_cvt_pk_bf16_f32 %0, %1, %1" : "=v"(rr) : "v"(hf));                 \
    *(HWP) = (short)rr;                                                       \
} while (0)

    for (int t = 0; t < T_LEN; t += 2) {
        const float2 xv2 = *(const float2*)(xp + t);   // one ds_read_b64
        STEP(hrd0, hwp1, xv2.x);
        __syncthreads();
        STEP(hrd1, hwp0, xv2.y);
        __syncthreads();
    }
#undef STEP

    // ---- epilogue: logits = W_lin @ h_T + b_lin, then log_softmax ----
    const float hfM = roleHi ? hf : 0.0f;    // only state-owner lanes count
    float p0 = W_lin[0 * HDIM + unit] * hfM;
    float p1 = W_lin[1 * HDIM + unit] * hfM;
    float p2 = W_lin[2 * HDIM + unit] * hfM;
    #pragma unroll
    for (int mm = 4; mm <= 32; mm <<= 1) {   // lanes with same lane&3 = batch
        p0 += __shfl_xor(p0, mm);
        p1 += __shfl_xor(p1, mm);
        p2 += __shfl_xor(p2, mm);
    }
    if (tid < BT * 3) ((float*)red)[tid] = 0.f;
    __syncthreads();
    if (lane < 4) {   // one partial per wave per batch
        atomicAdd(&red[lane][0], p0);
        atomicAdd(&red[lane][1], p1);
        atomicAdd(&red[lane][2], p2);
    }
    __syncthreads();
    if (tid < BT) {
        const float l0 = red[tid][0] + b_lin[0];
        const float l1 = red[tid][1] + b_lin[1];
        const float l2 = red[tid][2] + b_lin[2];
        const float m  = fmaxf(l0, fmaxf(l1, l2));
        const float sm = __expf(l0 - m) + __expf(l1 - m) + __expf(l2 - m);
        const float ls = __logf(sm);
        out[(b0 + tid) * 3 + 0] = l0 - m - ls;
        out[(b0 + tid) * 3 + 1] = l1 - m - ls;
        out[(b0 + tid) * 3 + 2] = l2 - m - ls;
    }
}

extern "C" void kernel_launch(void* const* d_in, const int* in_sizes, int n_in,
                              void* d_out, int out_size, void* d_ws, size_t ws_size,
                              hipStream_t stream) {
    const float* x     = (const float*)d_in[0];
    const float* W_ih  = (const float*)d_in[1];
    const float* W_hh  = (const float*)d_in[2];
    const float* b_ih  = (const float*)d_in[3];
    const float* b_hh  = (const float*)d_in[4];
    const float* W_lin = (const float*)d_in[5];
    const float* b_lin = (const float*)d_in[6];
    float* out = (float*)d_out;

    const int B = in_sizes[0] / T_LEN;   // 2048
    lstm_mfma_kernel<<<B / BT, 512, 0, stream>>>(x, W_ih, W_hh, b_ih, b_hh,
                                                 W_lin, b_lin, out);
}

// Round 10
// 521.243 us; speedup vs baseline: 1.4442x; 1.4442x over previous
//
#include <hip/hip_runtime.h>
#include <hip/hip_bf16.h>

#define T_LEN 2048
#define HDIM  64
#define BT    4            // batches per block -> 512 blocks = 2 blocks/CU
#define XS    (T_LEN + 4)  // x row stride (floats)
#define HS    72           // h_lds row stride in bf16
#define L2E   1.4426950408889634f   // log2(e)
#define L2E2  2.8853900817779268f   // 2*log2(e)

typedef __attribute__((ext_vector_type(8))) short bf16x8;
typedef __attribute__((ext_vector_type(4))) float f32x4;

__device__ __forceinline__ float rcp_f(float x)  { return __builtin_amdgcn_rcpf(x); }
__device__ __forceinline__ float exp2_f(float x) { return __builtin_amdgcn_exp2f(x); }
__device__ __forceinline__ unsigned short f2bf(float f) {
    unsigned int u = __float_as_uint(f);
    u += 0x7fffu + ((u >> 16) & 1u);
    return (unsigned short)(u >> 16);
}

// R8 structure (proven best): BT=4, 512 blocks = 2 independent blocks/CU
// (2 waves/SIMD, stochastic phase overlap); wave w owns 16 hidden units;
// 16 MFMA cols = 4 batches x 4 row-selects; each lane = exactly one
// (unit,batch) cell (issue-optimal: 512 lanes / 512 cells per CU);
// weights prescaled into exp2 domain; zero-quad MFMA C-in; fused-rcp
// nonlinearities (8 trans/cell-step).
// R10 adds: s_setprio(1) around the post-barrier ds_read+MFMA cluster
// (T5 regime: independent wave groups arbitrating, not lockstep), and a
// x4-unrolled t-loop. (R9 showed splitting the cell across lane pairs
// lengthens the serial chain via shfl and loses; R7 showed 1 block/CU
// static interleave loses to 2-block overlap.)
__global__ __launch_bounds__(256, 2) void lstm_mfma_kernel(
    const float* __restrict__ x,      // [B, T, 1]
    const float* __restrict__ W_ih,   // [4H, 1]
    const float* __restrict__ W_hh,   // [4H, H]
    const float* __restrict__ b_ih,   // [4H]
    const float* __restrict__ b_hh,   // [4H]
    const float* __restrict__ W_lin,  // [3, H]
    const float* __restrict__ b_lin,  // [3]
    float* __restrict__ out)          // [B, 3]
{
    const int tid  = threadIdx.x;
    const int lane = tid & 63;
    const int wv   = tid >> 6;       // wave 0..3
    const int col  = lane & 15;
    const int hi   = lane >> 4;      // k/row subgroup
    const int bq   = col & 3;        // batch serviced by this lane
    const int s    = col >> 2;       // C/D reg select: row = hi*4 + s
    const int b0   = blockIdx.x * BT;

    __shared__ float sx[BT][XS];
    __shared__ short hl[2][BT][HS];
    __shared__ float red[BT][3];

    for (int i = tid; i < 2 * BT * HS; i += 256) ((short*)hl)[i] = 0;

    // ---- stage all T for the 4 batches (coalesced float4) ----
    #pragma unroll
    for (int q = 0; q < 8; ++q) {
        const int idx = q * 256 + tid;
        const int row = idx >> 9;
        const int c4  = idx & 511;
        *(float4*)&sx[row][c4 * 4] =
            ((const float4*)(x + (size_t)(b0 + row) * T_LEN))[c4];
    }

    // ---- resident W_hh A-fragments (bf16), prescaled into exp2 domain ----
    const float scl[4] = {L2E, L2E, L2E2, L2E};   // i,f sigmoid; g tanh(2x); o sigmoid
    bf16x8 wf[4][2];
    #pragma unroll
    for (int g = 0; g < 4; ++g) {
        const int rowA = 64 * g + 16 * wv + col;
        #pragma unroll
        for (int kc = 0; kc < 2; ++kc) {
            const float* p = W_hh + rowA * HDIM + kc * 32 + hi * 8;
            bf16x8 f;
            #pragma unroll
            for (int j = 0; j < 8; ++j) f[j] = (short)f2bf(p[j] * scl[g]);
            wf[g][kc] = f;
        }
    }
    float wih1[4], bias1[4];
    #pragma unroll
    for (int g = 0; g < 4; ++g) {
        const int row = 64 * g + 16 * wv + hi * 4 + s;
        wih1[g]  = W_ih[row] * scl[g];
        bias1[g] = (b_ih[row] + b_hh[row]) * scl[g];
    }

    float cst = 0.f, hf = 0.f;
    const int sb0 = s & 1, sb1 = s >> 1;
    const int hwr = 16 * wv + hi * 4 + s;
    const int hi8 = hi * 8;

    const f32x4 zq = {0.f, 0.f, 0.f, 0.f};   // persistent MFMA C-in

    // static double-buffer pointers: zero per-step address arithmetic
    const short* hrd0 = &hl[0][bq][0];
    const short* hrd1 = &hl[1][bq][0];
    short* hwp1 = &hl[1][bq][hwr];
    short* hwp0 = &hl[0][bq][hwr];
    const float* xp = &sx[bq][0];

    __syncthreads();   // covers hl zero-init + sx staging

#define STEP(HRD, HWP, XV) do {                                               \
    const bf16x8 hb0 = *(const bf16x8*)((HRD) + hi8);                         \
    const bf16x8 hb1 = *(const bf16x8*)((HRD) + 32 + hi8);                    \
    __builtin_amdgcn_s_setprio(1);                                            \
    f32x4 a0 = __builtin_amdgcn_mfma_f32_16x16x32_bf16(wf[0][0], hb0, zq, 0, 0, 0); \
    f32x4 a1 = __builtin_amdgcn_mfma_f32_16x16x32_bf16(wf[1][0], hb0, zq, 0, 0, 0); \
    f32x4 a2 = __builtin_amdgcn_mfma_f32_16x16x32_bf16(wf[2][0], hb0, zq, 0, 0, 0); \
    f32x4 a3 = __builtin_amdgcn_mfma_f32_16x16x32_bf16(wf[3][0], hb0, zq, 0, 0, 0); \
    a0 = __builtin_amdgcn_mfma_f32_16x16x32_bf16(wf[0][1], hb1, a0, 0, 0, 0); \
    a1 = __builtin_amdgcn_mfma_f32_16x16x32_bf16(wf[1][1], hb1, a1, 0, 0, 0); \
    a2 = __builtin_amdgcn_mfma_f32_16x16x32_bf16(wf[2][1], hb1, a2, 0, 0, 0); \
    a3 = __builtin_amdgcn_mfma_f32_16x16x32_bf16(wf[3][1], hb1, a3, 0, 0, 0); \
    __builtin_amdgcn_s_setprio(0);                                            \
    const float g0 = (sb1 ? (sb0 ? a0[3] : a0[2]) : (sb0 ? a0[1] : a0[0]))    \
                     + (bias1[0] + wih1[0] * (XV));                           \
    const float g1 = (sb1 ? (sb0 ? a1[3] : a1[2]) : (sb0 ? a1[1] : a1[0]))    \
                     + (bias1[1] + wih1[1] * (XV));                           \
    const float g2 = (sb1 ? (sb0 ? a2[3] : a2[2]) : (sb0 ? a2[1] : a2[0]))    \
                     + (bias1[2] + wih1[2] * (XV));                           \
    const float g3 = (sb1 ? (sb0 ? a3[3] : a3[2]) : (sb0 ? a3[1] : a3[0]))    \
                     + (bias1[3] + wih1[3] * (XV));                           \
    const float e0 = exp2_f(-g0);                                             \
    const float e1 = exp2_f(-g1);                                             \
    const float e2 = exp2_f(g2);                                              \
    const float e3 = exp2_f(-g3);                                             \
    const float fv = rcp_f(1.0f + e1);                                        \
    const float ig = (e2 - 1.0f) * rcp_f((1.0f + e0) * (e2 + 1.0f));          \
    cst = fv * cst + ig;                                                      \
    const float cc = fminf(cst, 32.0f);    /* tanh(32)==1 in fp32; no inf */  \
    const float eC = exp2_f(L2E2 * cc);                                       \
    hf = (eC - 1.0f) * rcp_f((1.0f + e3) * (eC + 1.0f));                      \
    unsigned int rr;                                                          \
    asm("v_cvt_pk_bf16_f32 %0, %1, %1" : "=v"(rr) : "v"(hf));                 \
    *(HWP) = (short)rr;                                                       \
} while (0)

    for (int t = 0; t < T_LEN; t += 4) {
        const float4 xv4 = *(const float4*)(xp + t);   // one ds_read_b128
        STEP(hrd0, hwp1, xv4.x);
        __syncthreads();
        STEP(hrd1, hwp0, xv4.y);
        __syncthreads();
        STEP(hrd0, hwp1, xv4.z);
        __syncthreads();
        STEP(hrd1, hwp0, xv4.w);
        __syncthreads();
    }
#undef STEP

    // ---- epilogue: logits = W_lin @ h_T + b_lin, then log_softmax ----
    float p0 = W_lin[0 * HDIM + hwr] * hf;
    float p1 = W_lin[1 * HDIM + hwr] * hf;
    float p2 = W_lin[2 * HDIM + hwr] * hf;
    #pragma unroll
    for (int m = 4; m <= 32; m <<= 1) {
        p0 += __shfl_xor(p0, m);
        p1 += __shfl_xor(p1, m);
        p2 += __shfl_xor(p2, m);
    }
    if (tid < BT * 3) ((float*)red)[tid] = 0.f;
    __syncthreads();
    if (lane < 4) {
        atomicAdd(&red[lane][0], p0);
        atomicAdd(&red[lane][1], p1);
        atomicAdd(&red[lane][2], p2);
    }
    __syncthreads();
    if (tid < BT) {
        const float l0 = red[tid][0] + b_lin[0];
        const float l1 = red[tid][1] + b_lin[1];
        const float l2 = red[tid][2] + b_lin[2];
        const float m  = fmaxf(l0, fmaxf(l1, l2));
        const float sm = __expf(l0 - m) + __expf(l1 - m) + __expf(l2 - m);
        const float ls = __logf(sm);
        out[(b0 + tid) * 3 + 0] = l0 - m - ls;
        out[(b0 + tid) * 3 + 1] = l1 - m - ls;
        out[(b0 + tid) * 3 + 2] = l2 - m - ls;
    }
}

extern "C" void kernel_launch(void* const* d_in, const int* in_sizes, int n_in,
                              void* d_out, int out_size, void* d_ws, size_t ws_size,
                              hipStream_t stream) {
    const float* x     = (const float*)d_in[0];
    const float* W_ih  = (const float*)d_in[1];
    const float* W_hh  = (const float*)d_in[2];
    const float* b_ih  = (const float*)d_in[3];
    const float* b_hh  = (const float*)d_in[4];
    const float* W_lin = (const float*)d_in[5];
    const float* b_lin = (const float*)d_in[6];
    float* out = (float*)d_out;

    const int B = in_sizes[0] / T_LEN;   // 2048
    lstm_mfma_kernel<<<B / BT, 256, 0, stream>>>(x, W_ih, W_hh, b_ih, b_hh,
                                                 W_lin, b_lin, out);
}

// Round 11
// 511.985 us; speedup vs baseline: 1.4703x; 1.0181x over previous
//
#include <hip/hip_runtime.h>
#include <hip/hip_bf16.h>

#define T_LEN 2048
#define HDIM  64
#define BT    4            // batches per block -> 512 blocks = 2 blocks/CU
#define XS    (T_LEN + 4)  // x row stride (floats)
#define HS    72           // h_lds row stride in bf16
#define L2E   1.4426950408889634f   // log2(e)
#define L2E2  2.8853900817779268f   // 2*log2(e)

typedef __attribute__((ext_vector_type(8))) short bf16x8;
typedef __attribute__((ext_vector_type(4))) float f32x4;

__device__ __forceinline__ float rcp_f(float x)  { return __builtin_amdgcn_rcpf(x); }
__device__ __forceinline__ float exp2_f(float x) { return __builtin_amdgcn_exp2f(x); }
__device__ __forceinline__ unsigned short f2bf(float f) {
    unsigned int u = __float_as_uint(f);
    u += 0x7fffu + ((u >> 16) & 1u);
    return (unsigned short)(u >> 16);
}

// R8/R10 structure (proven local optimum): BT=4, 512 blocks = 2 independent
// blocks/CU (stochastic phase overlap); wave w owns 16 hidden units; 16 MFMA
// cols = 4 batches x 4 row-selects; each lane = exactly one (unit,batch)
// cell; exp2-domain prescaled weights; setprio(1) on the ds_read+MFMA
// cluster; x4-unrolled t-loop.
// R11 diet: (1) bias-in-C -- the MFMA C-in quad carries the per-row biases
// (reg r = row hi*4+r bias), so the gate add collapses to one FMA
// (wih*xv + sel); quads persist across steps since MFMA D != C.
// (2) merged fv/ig reciprocal: cst' = (cst*t + (e2-1)(1+e1)) * rcp(t*(1+e1)),
// t = (1+e0)(e2+1) -- 8 -> 7 transcendentals per step.
// (Failed alternatives, measured: R7 1-block static interleave; R9 lane-pair
// split; analyzed: M-side batching starves the 256-CU grid, BT=2 doubles
// per-cell issue, broadcast-B wave-per-batch needs 60 cndmask/step.)
__global__ __launch_bounds__(256, 2) void lstm_mfma_kernel(
    const float* __restrict__ x,      // [B, T, 1]
    const float* __restrict__ W_ih,   // [4H, 1]
    const float* __restrict__ W_hh,   // [4H, H]
    const float* __restrict__ b_ih,   // [4H]
    const float* __restrict__ b_hh,   // [4H]
    const float* __restrict__ W_lin,  // [3, H]
    const float* __restrict__ b_lin,  // [3]
    float* __restrict__ out)          // [B, 3]
{
    const int tid  = threadIdx.x;
    const int lane = tid & 63;
    const int wv   = tid >> 6;       // wave 0..3
    const int col  = lane & 15;
    const int hi   = lane >> 4;      // k/row subgroup
    const int bq   = col & 3;        // batch serviced by this lane
    const int s    = col >> 2;       // C/D reg select: row = hi*4 + s
    const int b0   = blockIdx.x * BT;

    __shared__ float sx[BT][XS];
    __shared__ short hl[2][BT][HS];
    __shared__ float red[BT][3];

    for (int i = tid; i < 2 * BT * HS; i += 256) ((short*)hl)[i] = 0;

    // ---- stage all T for the 4 batches (coalesced float4) ----
    #pragma unroll
    for (int q = 0; q < 8; ++q) {
        const int idx = q * 256 + tid;
        const int row = idx >> 9;
        const int c4  = idx & 511;
        *(float4*)&sx[row][c4 * 4] =
            ((const float4*)(x + (size_t)(b0 + row) * T_LEN))[c4];
    }

    // ---- resident W_hh A-fragments (bf16), prescaled into exp2 domain ----
    const float scl[4] = {L2E, L2E, L2E2, L2E};   // i,f sigmoid; g tanh(2x); o sigmoid
    bf16x8 wf[4][2];
    #pragma unroll
    for (int g = 0; g < 4; ++g) {
        const int rowA = 64 * g + 16 * wv + col;
        #pragma unroll
        for (int kc = 0; kc < 2; ++kc) {
            const float* p = W_hh + rowA * HDIM + kc * 32 + hi * 8;
            bf16x8 f;
            #pragma unroll
            for (int j = 0; j < 8; ++j) f[j] = (short)f2bf(p[j] * scl[g]);
            wf[g][kc] = f;
        }
    }
    // per-lane constants: wih for the selected row; bias QUADS for MFMA C-in
    // (reg r must carry row hi*4+r's bias so whichever reg a lane consumes is
    // correct)
    float wih1[4];
    f32x4 bq4[4];
    #pragma unroll
    for (int g = 0; g < 4; ++g) {
        wih1[g] = W_ih[64 * g + 16 * wv + hi * 4 + s] * scl[g];
        #pragma unroll
        for (int r = 0; r < 4; ++r) {
            const int row = 64 * g + 16 * wv + hi * 4 + r;
            bq4[g][r] = (b_ih[row] + b_hh[row]) * scl[g];
        }
    }

    float cst = 0.f, hf = 0.f;
    const int sb0 = s & 1, sb1 = s >> 1;
    const int hwr = 16 * wv + hi * 4 + s;
    const int hi8 = hi * 8;

    // static double-buffer pointers: zero per-step address arithmetic
    const short* hrd0 = &hl[0][bq][0];
    const short* hrd1 = &hl[1][bq][0];
    short* hwp1 = &hl[1][bq][hwr];
    short* hwp0 = &hl[0][bq][hwr];
    const float* xp = &sx[bq][0];

    __syncthreads();   // covers hl zero-init + sx staging

#define STEP(HRD, HWP, XV) do {                                               \
    const bf16x8 hb0 = *(const bf16x8*)((HRD) + hi8);                         \
    const bf16x8 hb1 = *(const bf16x8*)((HRD) + 32 + hi8);                    \
    __builtin_amdgcn_s_setprio(1);                                            \
    f32x4 a0 = __builtin_amdgcn_mfma_f32_16x16x32_bf16(wf[0][0], hb0, bq4[0], 0, 0, 0); \
    f32x4 a1 = __builtin_amdgcn_mfma_f32_16x16x32_bf16(wf[1][0], hb0, bq4[1], 0, 0, 0); \
    f32x4 a2 = __builtin_amdgcn_mfma_f32_16x16x32_bf16(wf[2][0], hb0, bq4[2], 0, 0, 0); \
    f32x4 a3 = __builtin_amdgcn_mfma_f32_16x16x32_bf16(wf[3][0], hb0, bq4[3], 0, 0, 0); \
    a0 = __builtin_amdgcn_mfma_f32_16x16x32_bf16(wf[0][1], hb1, a0, 0, 0, 0); \
    a1 = __builtin_amdgcn_mfma_f32_16x16x32_bf16(wf[1][1], hb1, a1, 0, 0, 0); \
    a2 = __builtin_amdgcn_mfma_f32_16x16x32_bf16(wf[2][1], hb1, a2, 0, 0, 0); \
    a3 = __builtin_amdgcn_mfma_f32_16x16x32_bf16(wf[3][1], hb1, a3, 0, 0, 0); \
    __builtin_amdgcn_s_setprio(0);                                            \
    const float g0 = wih1[0] * (XV)                                           \
        + (sb1 ? (sb0 ? a0[3] : a0[2]) : (sb0 ? a0[1] : a0[0]));              \
    const float g1 = wih1[1] * (XV)                                           \
        + (sb1 ? (sb0 ? a1[3] : a1[2]) : (sb0 ? a1[1] : a1[0]));              \
    const float g2 = wih1[2] * (XV)                                           \
        + (sb1 ? (sb0 ? a2[3] : a2[2]) : (sb0 ? a2[1] : a2[0]));              \
    const float g3 = wih1[3] * (XV)                                           \
        + (sb1 ? (sb0 ? a3[3] : a3[2]) : (sb0 ? a3[1] : a3[0]));              \
    const float e0 = exp2_f(-g0);                                             \
    const float e1 = exp2_f(-g1);                                             \
    const float e2 = exp2_f(g2);                                              \
    const float e3 = exp2_f(-g3);                                             \
    const float A1 = 1.0f + e0;                                               \
    const float A2 = e2 + 1.0f;                                               \
    const float A3 = 1.0f + e1;                                               \
    const float A4 = e2 - 1.0f;                                               \
    const float tt = A1 * A2;                                                 \
    const float Dd = tt * A3;                                                 \
    const float Nn = cst * tt + A4 * A3;                                      \
    cst = Nn * rcp_f(Dd);                                                     \
    const float cc = fminf(cst, 32.0f);    /* tanh(32)==1 in fp32; no inf */  \
    const float eC = exp2_f(L2E2 * cc);                                       \
    hf = (eC - 1.0f) * rcp_f((1.0f + e3) * (eC + 1.0f));                      \
    unsigned int rr;                                                          \
    asm("v_cvt_pk_bf16_f32 %0, %1, %1" : "=v"(rr) : "v"(hf));                 \
    *(HWP) = (short)rr;                                                       \
} while (0)

    for (int t = 0; t < T_LEN; t += 4) {
        const float4 xv4 = *(const float4*)(xp + t);   // one ds_read_b128
        STEP(hrd0, hwp1, xv4.x);
        __syncthreads();
        STEP(hrd1, hwp0, xv4.y);
        __syncthreads();
        STEP(hrd0, hwp1, xv4.z);
        __syncthreads();
        STEP(hrd1, hwp0, xv4.w);
        __syncthreads();
    }
#undef STEP

    // ---- epilogue: logits = W_lin @ h_T + b_lin, then log_softmax ----
    float p0 = W_lin[0 * HDIM + hwr] * hf;
    float p1 = W_lin[1 * HDIM + hwr] * hf;
    float p2 = W_lin[2 * HDIM + hwr] * hf;
    #pragma unroll
    for (int m = 4; m <= 32; m <<= 1) {
        p0 += __shfl_xor(p0, m);
        p1 += __shfl_xor(p1, m);
        p2 += __shfl_xor(p2, m);
    }
    if (tid < BT * 3) ((float*)red)[tid] = 0.f;
    __syncthreads();
    if (lane < 4) {
        atomicAdd(&red[lane][0], p0);
        atomicAdd(&red[lane][1], p1);
        atomicAdd(&red[lane][2], p2);
    }
    __syncthreads();
    if (tid < BT) {
        const float l0 = red[tid][0] + b_lin[0];
        const float l1 = red[tid][1] + b_lin[1];
        const float l2 = red[tid][2] + b_lin[2];
        const float m  = fmaxf(l0, fmaxf(l1, l2));
        const float sm = __expf(l0 - m) + __expf(l1 - m) + __expf(l2 - m);
        const float ls = __logf(sm);
        out[(b0 + tid) * 3 + 0] = l0 - m - ls;
        out[(b0 + tid) * 3 + 1] = l1 - m - ls;
        out[(b0 + tid) * 3 + 2] = l2 - m - ls;
    }
}

extern "C" void kernel_launch(void* const* d_in, const int* in_sizes, int n_in,
                              void* d_out, int out_size, void* d_ws, size_t ws_size,
                              hipStream_t stream) {
    const float* x     = (const float*)d_in[0];
    const float* W_ih  = (const float*)d_in[1];
    const float* W_hh  = (const float*)d_in[2];
    const float* b_ih  = (const float*)d_in[3];
    const float* b_hh  = (const float*)d_in[4];
    const float* W_lin = (const float*)d_in[5];
    const float* b_lin = (const float*)d_in[6];
    float* out = (float*)d_out;

    const int B = in_sizes[0] / T_LEN;   // 2048
    lstm_mfma_kernel<<<B / BT, 256, 0, stream>>>(x, W_ih, W_hh, b_ih, b_hh,
                                                 W_lin, b_lin, out);
}